// Round 4
// baseline (215.411 us; speedup 1.0000x reference)
//
#include <hip/hip_runtime.h>
#include <hip/hip_bf16.h>
#include <stdint.h>

// Problem dims
#define B_ROWS 8192
#define D_DIM  1024
#define C_CLS  1000
#define K_PROT 8
#define N_PAD  8192          // 32 * 256 (classes 1000..1023 are zero pads)
#define BK     32            // K-tile depth (elements) per ring slot
#define NT     32            // D_DIM / BK
#define SLOTB  32768         // ring slot: A 16KB + B 16KB
#define BOFF   16384

typedef __attribute__((ext_vector_type(8))) short  short8;   // 8 bf16
typedef __attribute__((ext_vector_type(4))) float  f32x4;    // MFMA acc

// --- helpers -------------------------------------------------------------

__device__ __forceinline__ ushort f2bf(float f) {
    union { float f; uint32_t u; } v; v.f = f;
    uint32_t u = v.u;
    return (ushort)((u + 0x7fffu + ((u >> 16) & 1u)) >> 16);
}

typedef __attribute__((address_space(1))) void gv_t;
typedef __attribute__((address_space(3))) void lv_t;

__device__ __forceinline__ void gload_lds16(const void* g, void* l) {
    // async global->LDS, 16B/lane; LDS dest = wave-uniform base + lane*16
    __builtin_amdgcn_global_load_lds((gv_t*)g, (lv_t*)l, 16, 0, 0);
}

__device__ __forceinline__ float waveReduceSum(float s) {
    #pragma unroll
    for (int m = 32; m >= 1; m >>= 1) s += __shfl_xor(s, m);
    return s;
}

// --- kernel 1: normalize weight_v rows -> bf16, PERMUTED + padded ---------
// Physical column P: gpan=P>>6, ni=(P>>4)&3, cc=P&15
//   class = gpan*8 + (cc&7),  k = ni + 4*(cc>>3)
// -> in the GEMM epilogue all 8 k's of a class live in lane pair (lane,lane^8).

__global__ __launch_bounds__(256) void prep_z(const float* __restrict__ wv,
                                              ushort* __restrict__ zb) {
    const int P = blockIdx.x;
    const int t = threadIdx.x;
    __shared__ float red[4];

    const int gpan = P >> 6;
    const int ni   = (P >> 4) & 3;
    const int cc   = P & 15;
    const int cls  = gpan * 8 + (cc & 7);
    const int k    = ni + ((cc >> 3) << 2);

    if (cls >= C_CLS) {
        ((ushort4*)(zb + (size_t)P * D_DIM))[t] = make_ushort4(0, 0, 0, 0);
        return;
    }
    const int n = cls * K_PROT + k;
    const float4 v = ((const float4*)(wv + (size_t)n * D_DIM))[t];
    float s = v.x*v.x + v.y*v.y + v.z*v.z + v.w*v.w;
    s = waveReduceSum(s);
    if ((t & 63) == 0) red[t >> 6] = s;
    __syncthreads();
    const float n2 = red[0] + red[1] + red[2] + red[3];
    const float rn = 1.0f / fmaxf(sqrtf(n2), 1e-15f);
    ushort4 o;
    o.x = f2bf(v.x * rn); o.y = f2bf(v.y * rn);
    o.z = f2bf(v.z * rn); o.w = f2bf(v.w * rn);
    ((ushort4*)(zb + (size_t)P * D_DIM))[t] = o;
}

// --- kernel 2: x -> bf16 + cx2 = sum(x^2) ---------------------------------

__global__ __launch_bounds__(256) void prep_x(const float* __restrict__ x,
                                              ushort* __restrict__ xb,
                                              float* __restrict__ cx2) {
    const int b = blockIdx.x;
    const int t = threadIdx.x;
    __shared__ float red[4];

    const float4 v = ((const float4*)(x + (size_t)b * D_DIM))[t];
    ushort4 o;
    o.x = f2bf(v.x); o.y = f2bf(v.y); o.z = f2bf(v.z); o.w = f2bf(v.w);
    ((ushort4*)(xb + (size_t)b * D_DIM))[t] = o;

    float s = v.x*v.x + v.y*v.y + v.z*v.z + v.w*v.w;
    s = waveReduceSum(s);
    if ((t & 63) == 0) red[t >> 6] = s;
    __syncthreads();
    if (t == 0) cx2[b] = red[0] + red[1] + red[2] + red[3];
}

// --- kernel 3: 256x256 tile, 8 waves, 4-slot LDS ring, counted vmcnt ------
// Ring slot (c&3) holds K-tile c (A 256x32 + B 256x32 bf16). While computing
// K-tile c (2 phases), stage K-tile c+3 into slot (c-1)&3 (retired at end of
// K-tile c-1). Drain before K-tile c+1's reads: vmcnt(8) = stages of c+2,c+3
// still in flight. T2 swizzle: 16B-slot p_phys = p_log ^ ((row>>1)&3),
// applied on the global SOURCE column at stage time and on the read address.

__global__ __launch_bounds__(512, 2) void gemm_epi(
        const ushort* __restrict__ A,    // [B_ROWS][D_DIM] bf16 (x)
        const ushort* __restrict__ Bz,   // [N_PAD][D_DIM] bf16 (permuted z)
        const float*  __restrict__ cx2g, // [B_ROWS]
        const float*  __restrict__ wgl,  // [C_CLS]
        const float*  __restrict__ gamma_p,
        float*        __restrict__ out)  // [B_ROWS][C_CLS]
{
    __shared__ __attribute__((aligned(128))) char lds[4 * SLOTB]; // 128 KiB

    const int tid  = threadIdx.x;
    const int lane = tid & 63;
    const int wid  = tid >> 6;        // 0..7
    const int wm   = wid >> 2;        // 0..1 : 128 output rows each
    const int wn   = wid & 3;         // 0..3 : 64 output cols each

    // T1: XCD x owns bn in {4x..4x+3} (2 MB of B panels, L2-resident)
    const int bid = blockIdx.x;       // 0..1023
    const int bm  = (bid >> 3) & 31;
    const int bn  = 4 * (bid & 7) + (bid >> 8);
    const int m0  = bm * 256;
    const int n0  = bn * 256;

    // staging geometry: thread t covers row rSt (+128 for 2nd gload),
    // physical 16B-slot tid&3; source col-group = (tid&3) ^ ((row>>1)&3)
    const int rSt = tid >> 2;                        // 0..127
    const int cSt = (tid & 3) ^ ((tid >> 3) & 3);
    const ushort* aS0 = A  + (size_t)(m0 + rSt) * D_DIM + cSt * 8;
    const ushort* aS1 = aS0 + (size_t)128 * D_DIM;
    const ushort* bS0 = Bz + (size_t)(n0 + rSt) * D_DIM + cSt * 8;
    const ushort* bS1 = bS0 + (size_t)128 * D_DIM;
    const int ldsW = wid * 1024;      // wave-uniform LDS sub-base

    // fragment read addressing (row stride 64B, swizzled 16B slot)
    const int swz = ((lane >> 4) ^ ((lane & 6) >> 1)) * 16;
    const int aOf = (wm * 128 + (lane & 15)) * 64 + swz;   // + mi*1024
    const int bOf = (wn * 64  + (lane & 15)) * 64 + swz;   // + ni*1024

#define STAGE_A(ct) do { char* sb_ = lds + ((ct) & 3) * SLOTB; \
    const int kq_ = (ct) * BK; \
    gload_lds16(aS0 + kq_, sb_ + ldsW); \
    gload_lds16(aS1 + kq_, sb_ + 8192 + ldsW); } while (0)
#define STAGE_B(ct) do { char* sb_ = lds + ((ct) & 3) * SLOTB + BOFF; \
    const int kq_ = (ct) * BK; \
    gload_lds16(bS0 + kq_, sb_ + ldsW); \
    gload_lds16(bS1 + kq_, sb_ + 8192 + ldsW); } while (0)
#define FENCE() asm volatile("" ::: "memory")

    f32x4 acc[8][4];
    #pragma unroll
    for (int i = 0; i < 8; ++i)
        #pragma unroll
        for (int j = 0; j < 4; ++j) acc[i][j] = (f32x4)(0.0f);

    // prologue: K-tiles 0,1,2 in flight; drain K0 (8 newer outstanding)
    STAGE_A(0); STAGE_B(0); STAGE_A(1); STAGE_B(1); STAGE_A(2); STAGE_B(2);
    asm volatile("s_waitcnt vmcnt(8)" ::: "memory");
    __builtin_amdgcn_s_barrier();
    FENCE();

    for (int c = 0; c < NT; ++c) {
        const char* As = lds + (c & 3) * SLOTB;
        const char* Bs = As + BOFF;
        short8 a[4], b[4];
        // ---- phase 0: a[0..3], b[0..3]; stage A(c+3); MFMA mi 0-3 ----
        #pragma unroll
        for (int mi = 0; mi < 4; ++mi)
            a[mi] = *(const short8*)(As + aOf + mi * 1024);
        #pragma unroll
        for (int ni = 0; ni < 4; ++ni)
            b[ni] = *(const short8*)(Bs + bOf + ni * 1024);
        if (c <= NT - 4) STAGE_A(c + 3);
        FENCE();
        __builtin_amdgcn_s_barrier();
        FENCE();
        __builtin_amdgcn_s_setprio(1);
        #pragma unroll
        for (int mi = 0; mi < 4; ++mi)
            #pragma unroll
            for (int ni = 0; ni < 4; ++ni)
                acc[mi][ni] = __builtin_amdgcn_mfma_f32_16x16x32_bf16(
                    a[mi], b[ni], acc[mi][ni], 0, 0, 0);
        __builtin_amdgcn_s_setprio(0);
        FENCE();
        __builtin_amdgcn_s_barrier();
        FENCE();
        // ---- phase 1: a[4..7]; stage B(c+3); MFMA mi 4-7; drain ----
        #pragma unroll
        for (int mi = 0; mi < 4; ++mi)
            a[mi] = *(const short8*)(As + aOf + (mi + 4) * 1024);
        if (c <= NT - 4) STAGE_B(c + 3);
        FENCE();
        __builtin_amdgcn_s_barrier();
        FENCE();
        __builtin_amdgcn_s_setprio(1);
        #pragma unroll
        for (int mi = 0; mi < 4; ++mi)
            #pragma unroll
            for (int ni = 0; ni < 4; ++ni)
                acc[mi + 4][ni] = __builtin_amdgcn_mfma_f32_16x16x32_bf16(
                    a[mi], b[ni], acc[mi + 4][ni], 0, 0, 0);
        __builtin_amdgcn_s_setprio(0);
        if (c <= NT - 4)      asm volatile("s_waitcnt vmcnt(8)" ::: "memory");
        else if (c == NT - 3) asm volatile("s_waitcnt vmcnt(4)" ::: "memory");
        else if (c == NT - 2) asm volatile("s_waitcnt vmcnt(0)" ::: "memory");
        __builtin_amdgcn_s_barrier();
        FENCE();
    }

    // ---- fused epilogue: hyperbolic logits + lane-pair logsumexp ---------
    __syncthreads();
    float* scx = (float*)lds;
    if (tid < 256) scx[tid] = cx2g[m0 + tid];
    __syncthreads();

    const float gam = gamma_p[0];
    const float ex  = expf(2.0f * gam);
    const float ch2 = ex + 1.0f / ex;           // 2*cosh(2*gamma)
    const float sh  = 0.5f * (ex - 1.0f / ex);  // sinh(2*gamma)

    const int  pan = (n0 >> 6) + wn;            // 64-col panel index
    const int  cls = pan * 8 + (lane & 7);
    const bool wrt = ((lane & 8) == 0) && (cls < C_CLS);
    const float w2 = (cls < C_CLS) ? 2.0f * wgl[cls] : 0.0f;

    #pragma unroll
    for (int mi = 0; mi < 8; ++mi) {
        #pragma unroll
        for (int r = 0; r < 4; ++r) {
            const int mloc = wm * 128 + mi * 16 + ((lane >> 4) << 2) + r;
            const float c2   = scx[mloc];
            const float rden = 1.0f / fmaxf(1.0f - c2, 1e-15f);
            const float tc   = ch2 * rden;
            const float tp   = (1.0f + c2) * sh * rden;
            float bk[4];
            #pragma unroll
            for (int ni = 0; ni < 4; ++ni) {
                const float t = fmaf(acc[mi][ni][r], tc, -tp);
                const float u = fmaxf(t + __fsqrt_rn(fmaf(t, t, 1.0f)), 1e-20f);
                bk[ni] = w2 * __logf(u);
            }
            float mx = fmaxf(fmaxf(bk[0], bk[1]), fmaxf(bk[2], bk[3]));
            mx = fmaxf(mx, __shfl_xor(mx, 8));
            float s = __expf(bk[0] - mx) + __expf(bk[1] - mx)
                    + __expf(bk[2] - mx) + __expf(bk[3] - mx);
            s += __shfl_xor(s, 8);
            if (wrt)
                out[(size_t)(m0 + mloc) * C_CLS + cls] = mx + __logf(s);
        }
    }
#undef STAGE_A
#undef STAGE_B
#undef FENCE
}

// --- launch ----------------------------------------------------------------

extern "C" void kernel_launch(void* const* d_in, const int* in_sizes, int n_in,
                              void* d_out, int out_size, void* d_ws, size_t ws_size,
                              hipStream_t stream) {
    const float* x     = (const float*)d_in[0];
    const float* wv    = (const float*)d_in[1];
    const float* wg    = (const float*)d_in[2];
    const float* gamma = (const float*)d_in[3];
    float* out = (float*)d_out;

    char* ws = (char*)d_ws;
    ushort* xb  = (ushort*)ws;                                  // 16,777,216 B
    ushort* zb  = (ushort*)(ws + (size_t)B_ROWS * D_DIM * 2);   // 16,777,216 B
    float*  cx2 = (float*)(ws + (size_t)B_ROWS * D_DIM * 2
                              + (size_t)N_PAD * D_DIM * 2);     //     32,768 B

    prep_z<<<N_PAD, 256, 0, stream>>>(wv, zb);
    prep_x<<<B_ROWS, 256, 0, stream>>>(x, xb, cx2);
    gemm_epi<<<1024, 512, 0, stream>>>(xb, zb, cx2, wg, gamma, out);
}

// Round 5
// 203.766 us; speedup vs baseline: 1.0572x; 1.0572x over previous
//
#include <hip/hip_runtime.h>
#include <hip/hip_bf16.h>
#include <stdint.h>

// Problem dims
#define B_ROWS 8192
#define D_DIM  1024
#define C_CLS  1000
#define K_PROT 8
#define N_PAD  8192          // 32 * 256 (classes 1000..1023 are zero pads)
#define BK     32            // K-tile depth (elements) per ring slot
#define NT     32            // D_DIM / BK
#define SLOTB  32768         // ring slot: A 16KB + B 16KB
#define BOFF   16384

typedef __attribute__((ext_vector_type(8))) short  short8;   // 8 bf16
typedef __attribute__((ext_vector_type(4))) float  f32x4;    // MFMA acc

// --- helpers -------------------------------------------------------------

__device__ __forceinline__ ushort f2bf(float f) {
    union { float f; uint32_t u; } v; v.f = f;
    uint32_t u = v.u;
    return (ushort)((u + 0x7fffu + ((u >> 16) & 1u)) >> 16);
}

typedef __attribute__((address_space(1))) void gv_t;
typedef __attribute__((address_space(3))) void lv_t;

__device__ __forceinline__ void gload_lds16(const void* g, void* l) {
    __builtin_amdgcn_global_load_lds((gv_t*)g, (lv_t*)l, 16, 0, 0);
}

__device__ __forceinline__ float waveReduceSum(float s) {
    #pragma unroll
    for (int m = 32; m >= 1; m >>= 1) s += __shfl_xor(s, m);
    return s;
}

// --- kernel 1: normalize weight_v rows -> bf16, PERMUTED + padded ---------
// Physical column P: gpan=P>>6, ni=(P>>4)&3, cc=P&15
//   class = gpan*8 + (cc&7),  k = ni + 4*(cc>>3)

__global__ __launch_bounds__(256) void prep_z(const float* __restrict__ wv,
                                              ushort* __restrict__ zb) {
    const int P = blockIdx.x;
    const int t = threadIdx.x;
    __shared__ float red[4];

    const int gpan = P >> 6;
    const int ni   = (P >> 4) & 3;
    const int cc   = P & 15;
    const int cls  = gpan * 8 + (cc & 7);
    const int k    = ni + ((cc >> 3) << 2);

    if (cls >= C_CLS) {
        ((ushort4*)(zb + (size_t)P * D_DIM))[t] = make_ushort4(0, 0, 0, 0);
        return;
    }
    const int n = cls * K_PROT + k;
    const float4 v = ((const float4*)(wv + (size_t)n * D_DIM))[t];
    float s = v.x*v.x + v.y*v.y + v.z*v.z + v.w*v.w;
    s = waveReduceSum(s);
    if ((t & 63) == 0) red[t >> 6] = s;
    __syncthreads();
    const float n2 = red[0] + red[1] + red[2] + red[3];
    const float rn = 1.0f / fmaxf(sqrtf(n2), 1e-15f);
    ushort4 o;
    o.x = f2bf(v.x * rn); o.y = f2bf(v.y * rn);
    o.z = f2bf(v.z * rn); o.w = f2bf(v.w * rn);
    ((ushort4*)(zb + (size_t)P * D_DIM))[t] = o;
}

// --- kernel 2: x -> bf16 + cx2 = sum(x^2) ---------------------------------

__global__ __launch_bounds__(256) void prep_x(const float* __restrict__ x,
                                              ushort* __restrict__ xb,
                                              float* __restrict__ cx2) {
    const int b = blockIdx.x;
    const int t = threadIdx.x;
    __shared__ float red[4];

    const float4 v = ((const float4*)(x + (size_t)b * D_DIM))[t];
    ushort4 o;
    o.x = f2bf(v.x); o.y = f2bf(v.y); o.z = f2bf(v.z); o.w = f2bf(v.w);
    ((ushort4*)(xb + (size_t)b * D_DIM))[t] = o;

    float s = v.x*v.x + v.y*v.y + v.z*v.z + v.w*v.w;
    s = waveReduceSum(s);
    if ((t & 63) == 0) red[t >> 6] = s;
    __syncthreads();
    if (t == 0) cx2[b] = red[0] + red[1] + red[2] + red[3];
}

// --- kernel 3: 256x256, 8 waves, 4-slot ring, ONE barrier per K-tile ------
// Per K-tile c: issue stage(c+3) into slot (c-1)&3 (disjoint from read slot
// c&3 -> race-free), 12 ds_read_b128, 32 MFMA (setprio-wrapped), counted
// vmcnt(8) keeping tiles c+2,c+3 in flight, one s_barrier. Waves drift
// between barriers -> MFMA of one wave overlaps ds_read/stage of another.

__global__ __launch_bounds__(512, 2) void gemm_epi(
        const ushort* __restrict__ A,    // [B_ROWS][D_DIM] bf16 (x)
        const ushort* __restrict__ Bz,   // [N_PAD][D_DIM] bf16 (permuted z)
        const float*  __restrict__ cx2g, // [B_ROWS]
        const float*  __restrict__ wgl,  // [C_CLS]
        const float*  __restrict__ gamma_p,
        float*        __restrict__ out)  // [B_ROWS][C_CLS]
{
    __shared__ __attribute__((aligned(128))) char lds[4 * SLOTB]; // 128 KiB

    const int tid  = threadIdx.x;
    const int lane = tid & 63;
    const int wid  = tid >> 6;        // 0..7
    const int wm   = wid >> 2;        // 0..1 : 128 output rows each
    const int wn   = wid & 3;         // 0..3 : 64 output cols each

    // Grid order: XCD x (= bid&7) owns region bm in [16s,16s+16), bn in
    // [8q,8q+8) with s=x>>2, q=x&3; bn fastest within the region so the
    // A-panel stays L2-hot for 8 consecutive blocks, B region = 4 MB = L2.
    const int bid = blockIdx.x;       // 0..1023
    const int x   = bid & 7;
    const int j   = bid >> 3;         // 0..127
    const int bm  = 16 * (x >> 2) + ((j >> 3) & 7) + 8 * (j >> 6);
    const int bn  = 8 * (x & 3) + (j & 7);
    const int m0  = bm * 256;
    const int n0  = bn * 256;

    // staging: thread t covers row rSt (+128 for 2nd gload), physical 16B
    // slot tid&3; source col-group = (tid&3) ^ ((row>>1)&3)   [T2 swizzle]
    const int rSt = tid >> 2;                        // 0..127
    const int cSt = (tid & 3) ^ ((tid >> 3) & 3);
    const ushort* aS0 = A  + (size_t)(m0 + rSt) * D_DIM + cSt * 8;
    const ushort* aS1 = aS0 + (size_t)128 * D_DIM;
    const ushort* bS0 = Bz + (size_t)(n0 + rSt) * D_DIM + cSt * 8;
    const ushort* bS1 = bS0 + (size_t)128 * D_DIM;
    const int ldsW = wid * 1024;      // wave-uniform LDS sub-base

    // fragment read addressing (row stride 64B, swizzled 16B slot)
    const int swz = ((lane >> 4) ^ ((lane & 6) >> 1)) * 16;
    const int aOf = (wm * 128 + (lane & 15)) * 64 + swz;   // + mi*1024
    const int bOf = (wn * 64  + (lane & 15)) * 64 + swz;   // + ni*1024

#define STAGE_A(ct) do { char* sb_ = lds + ((ct) & 3) * SLOTB; \
    const int kq_ = (ct) * BK; \
    gload_lds16(aS0 + kq_, sb_ + ldsW); \
    gload_lds16(aS1 + kq_, sb_ + 8192 + ldsW); } while (0)
#define STAGE_B(ct) do { char* sb_ = lds + ((ct) & 3) * SLOTB + BOFF; \
    const int kq_ = (ct) * BK; \
    gload_lds16(bS0 + kq_, sb_ + ldsW); \
    gload_lds16(bS1 + kq_, sb_ + 8192 + ldsW); } while (0)

    f32x4 acc[8][4];
    #pragma unroll
    for (int i = 0; i < 8; ++i)
        #pragma unroll
        for (int jj = 0; jj < 4; ++jj) acc[i][jj] = (f32x4)(0.0f);

    // prologue: tiles 0,1,2 in flight (12 loads); drain tile 0 (keep 8)
    STAGE_A(0); STAGE_B(0); STAGE_A(1); STAGE_B(1); STAGE_A(2); STAGE_B(2);
    asm volatile("s_waitcnt vmcnt(8)" ::: "memory");
    __builtin_amdgcn_s_barrier();
    asm volatile("" ::: "memory");

    for (int c = 0; c < NT; ++c) {
        // issue-early: stage tile c+3 (slot (c-1)&3, all reads retired)
        if (c < NT - 3) { STAGE_A(c + 3); STAGE_B(c + 3); }
        const char* As = lds + (c & 3) * SLOTB;
        const char* Bs = As + BOFF;
        short8 a[8], b[4];
        #pragma unroll
        for (int mi = 0; mi < 8; ++mi)
            a[mi] = *(const short8*)(As + aOf + mi * 1024);
        #pragma unroll
        for (int ni = 0; ni < 4; ++ni)
            b[ni] = *(const short8*)(Bs + bOf + ni * 1024);
        __builtin_amdgcn_s_setprio(1);
        #pragma unroll
        for (int mi = 0; mi < 8; ++mi)
            #pragma unroll
            for (int ni = 0; ni < 4; ++ni)
                acc[mi][ni] = __builtin_amdgcn_mfma_f32_16x16x32_bf16(
                    a[mi], b[ni], acc[mi][ni], 0, 0, 0);
        __builtin_amdgcn_s_setprio(0);
        // counted drain: keep tiles c+2,c+3 (8 loads) in flight
        if (c < NT - 3)       asm volatile("s_waitcnt vmcnt(8)" ::: "memory");
        else if (c == NT - 3) asm volatile("s_waitcnt vmcnt(4)" ::: "memory");
        else if (c == NT - 2) asm volatile("s_waitcnt vmcnt(0)" ::: "memory");
        __builtin_amdgcn_s_barrier();
        asm volatile("" ::: "memory");
    }

    // ---- fused epilogue: hyperbolic logits + lane-pair logsumexp ---------
    __syncthreads();
    float* scx = (float*)lds;
    if (tid < 256) scx[tid] = cx2g[m0 + tid];
    __syncthreads();

    const float gam = gamma_p[0];
    const float ex  = expf(2.0f * gam);
    const float ch2 = ex + 1.0f / ex;           // 2*cosh(2*gamma)
    const float sh  = 0.5f * (ex - 1.0f / ex);  // sinh(2*gamma)

    const int  pan = (n0 >> 6) + wn;            // 64-col panel index
    const int  cls = pan * 8 + (lane & 7);
    const bool wrt = ((lane & 8) == 0) && (cls < C_CLS);
    const float w2 = (cls < C_CLS) ? 2.0f * wgl[cls] : 0.0f;

    #pragma unroll
    for (int mi = 0; mi < 8; ++mi) {
        #pragma unroll
        for (int r = 0; r < 4; ++r) {
            const int mloc = wm * 128 + mi * 16 + ((lane >> 4) << 2) + r;
            const float c2   = scx[mloc];
            const float rden = 1.0f / fmaxf(1.0f - c2, 1e-15f);
            const float tc   = ch2 * rden;
            const float tp   = (1.0f + c2) * sh * rden;
            float bk[4];
            #pragma unroll
            for (int ni = 0; ni < 4; ++ni) {
                const float t = fmaf(acc[mi][ni][r], tc, -tp);
                const float u = fmaxf(t + __fsqrt_rn(fmaf(t, t, 1.0f)), 1e-20f);
                bk[ni] = w2 * __logf(u);
            }
            float mx = fmaxf(fmaxf(bk[0], bk[1]), fmaxf(bk[2], bk[3]));
            mx = fmaxf(mx, __shfl_xor(mx, 8));
            float s = __expf(bk[0] - mx) + __expf(bk[1] - mx)
                    + __expf(bk[2] - mx) + __expf(bk[3] - mx);
            s += __shfl_xor(s, 8);
            if (wrt)
                out[(size_t)(m0 + mloc) * C_CLS + cls] = mx + __logf(s);
        }
    }
#undef STAGE_A
#undef STAGE_B
}

// --- launch ----------------------------------------------------------------

extern "C" void kernel_launch(void* const* d_in, const int* in_sizes, int n_in,
                              void* d_out, int out_size, void* d_ws, size_t ws_size,
                              hipStream_t stream) {
    const float* x     = (const float*)d_in[0];
    const float* wv    = (const float*)d_in[1];
    const float* wg    = (const float*)d_in[2];
    const float* gamma = (const float*)d_in[3];
    float* out = (float*)d_out;

    char* ws = (char*)d_ws;
    ushort* xb  = (ushort*)ws;                                  // 16,777,216 B
    ushort* zb  = (ushort*)(ws + (size_t)B_ROWS * D_DIM * 2);   // 16,777,216 B
    float*  cx2 = (float*)(ws + (size_t)B_ROWS * D_DIM * 2
                              + (size_t)N_PAD * D_DIM * 2);     //     32,768 B

    prep_z<<<N_PAD, 256, 0, stream>>>(wv, zb);
    prep_x<<<B_ROWS, 256, 0, stream>>>(x, xb, cx2);
    gemm_epi<<<1024, 512, 0, stream>>>(xb, zb, cx2, wg, gamma, out);
}

// Round 6
// 170.669 us; speedup vs baseline: 1.2622x; 1.1939x over previous
//
#include <hip/hip_runtime.h>
#include <hip/hip_bf16.h>
#include <stdint.h>

// Problem dims
#define B_ROWS 8192
#define D_DIM  1024
#define C_CLS  1000
#define K_PROT 8
#define N_PAD  8064          // 63 * 128 zero-padded prototype columns
#define BM2    256
#define BN2    128
#define BKT    64            // K-tile depth (elements)
#define NTI    16            // D_DIM / BKT

typedef __attribute__((ext_vector_type(8))) short  short8;   // 8 bf16
typedef __attribute__((ext_vector_type(4))) float  f32x4;    // MFMA acc

// --- helpers -------------------------------------------------------------

__device__ __forceinline__ ushort f2bf(float f) {
    union { float f; uint32_t u; } v; v.f = f;
    uint32_t u = v.u;
    return (ushort)((u + 0x7fffu + ((u >> 16) & 1u)) >> 16);
}

typedef __attribute__((address_space(1))) void gv_t;
typedef __attribute__((address_space(3))) void lv_t;

__device__ __forceinline__ void gload_lds16(const void* g, void* l) {
    // async global->LDS, 16B/lane; LDS dest = wave-uniform base + lane*16
    __builtin_amdgcn_global_load_lds((gv_t*)g, (lv_t*)l, 16, 0, 0);
}

__device__ __forceinline__ float waveReduceSum(float s) {
    #pragma unroll
    for (int m = 32; m >= 1; m >>= 1) s += __shfl_xor(s, m);
    return s;
}

// --- kernel 1: normalize weight_v rows -> bf16, PERMUTED + padded ---------
// Physical column P: gpan=P>>6 (64-col panel), ni=(P>>4)&3, cc=P&15
//   class = gpan*8 + (cc&7),  k = ni + 4*(cc>>3)
// -> all 8 k's of a class live in the lane pair (lane, lane^8) of the epilogue.

__global__ __launch_bounds__(256) void prep_z(const float* __restrict__ wv,
                                              ushort* __restrict__ zb) {
    const int P = blockIdx.x;
    const int t = threadIdx.x;
    __shared__ float red[4];

    const int gpan = P >> 6;
    const int ni   = (P >> 4) & 3;
    const int cc   = P & 15;
    const int cls  = gpan * 8 + (cc & 7);
    const int k    = ni + ((cc >> 3) << 2);

    if (cls >= C_CLS) {
        ((ushort4*)(zb + (size_t)P * D_DIM))[t] = make_ushort4(0, 0, 0, 0);
        return;
    }
    const int n = cls * K_PROT + k;
    const float4 v = ((const float4*)(wv + (size_t)n * D_DIM))[t];
    float s = v.x*v.x + v.y*v.y + v.z*v.z + v.w*v.w;
    s = waveReduceSum(s);
    if ((t & 63) == 0) red[t >> 6] = s;
    __syncthreads();
    const float n2 = red[0] + red[1] + red[2] + red[3];
    const float rn = 1.0f / fmaxf(sqrtf(n2), 1e-15f);
    ushort4 o;
    o.x = f2bf(v.x * rn); o.y = f2bf(v.y * rn);
    o.z = f2bf(v.z * rn); o.w = f2bf(v.w * rn);
    ((ushort4*)(zb + (size_t)P * D_DIM))[t] = o;
}

// --- kernel 2: x -> bf16 + cx2 = sum(x^2) ---------------------------------

__global__ __launch_bounds__(256) void prep_x(const float* __restrict__ x,
                                              ushort* __restrict__ xb,
                                              float* __restrict__ cx2) {
    const int b = blockIdx.x;
    const int t = threadIdx.x;
    __shared__ float red[4];

    const float4 v = ((const float4*)(x + (size_t)b * D_DIM))[t];
    ushort4 o;
    o.x = f2bf(v.x); o.y = f2bf(v.y); o.z = f2bf(v.z); o.w = f2bf(v.w);
    ((ushort4*)(xb + (size_t)b * D_DIM))[t] = o;

    float s = v.x*v.x + v.y*v.y + v.z*v.z + v.w*v.w;
    s = waveReduceSum(s);
    if ((t & 63) == 0) red[t >> 6] = s;
    __syncthreads();
    if (t == 0) cx2[b] = red[0] + red[1] + red[2] + red[3];
}

// --- kernel 3: 256x128 block tile, 4 waves (128x64 each), R3 schedule -----
// Same 2-barrier K-loop as the proven R3 kernel; only the tile geometry
// changes: per-wave reuse 32 -> 42.7 FLOP per LDS byte (-25% LDS traffic).

__global__ __launch_bounds__(256, 2) void gemm_epi(
        const ushort* __restrict__ A,    // [B_ROWS][D_DIM] bf16 (x)
        const ushort* __restrict__ Bz,   // [N_PAD][D_DIM] bf16 (permuted z)
        const float*  __restrict__ cx2g, // [B_ROWS]
        const float*  __restrict__ wgl,  // [C_CLS]
        const float*  __restrict__ gamma_p,
        float*        __restrict__ out)  // [B_ROWS][C_CLS]
{
    __shared__ __attribute__((aligned(16))) ushort sA[BM2 * BKT]; // 32 KB
    __shared__ __attribute__((aligned(16))) ushort sB[BN2 * BKT]; // 16 KB

    const int tid  = threadIdx.x;
    const int lane = tid & 63;
    const int w    = tid >> 6;        // wave 0..3
    const int wm   = w >> 1;          // 0..1 : 128 output rows each
    const int wn   = w & 1;           // 0..1 : 64 output cols each

    // bm fastest: 32 consecutive blocks share one B-panel (256 KB L2-hot)
    const int bm = blockIdx.x & 31;
    const int bn = blockIdx.x >> 5;   // 0..62
    const int m0 = bm * BM2;
    const int n0 = bn * BN2;

    // staging: thread covers row (tid>>3) within each 32-row group; source
    // col-group = (lane&7) ^ (row&7)   [T2 swizzle, source side; row&7 = lane>>3]
    const int stCol = ((lane & 7) ^ (lane >> 3)) * 8;
    const ushort* aS = A  + (size_t)(m0 + (tid >> 3)) * D_DIM + stCol;
    const ushort* bS = Bz + (size_t)(n0 + (tid >> 3)) * D_DIM + stCol;

    // fragment read addressing (rows are 128 B; swizzled 16B slot)
    const int swz0 = ((      (lane >> 4) * 16) ^ ((lane & 7) << 4));
    const int swz1 = ((64 + ((lane >> 4) * 16)) ^ ((lane & 7) << 4));
    const char* sAb = (const char*)sA + (wm * 128 + (lane & 15)) * 128;
    const char* sBb = (const char*)sB + (wn * 64  + (lane & 15)) * 128;

    f32x4 acc[8][4];
    #pragma unroll
    for (int mi = 0; mi < 8; ++mi)
        #pragma unroll
        for (int ni = 0; ni < 4; ++ni)
            acc[mi][ni] = (f32x4)(0.0f);

    for (int t = 0; t < NTI; ++t) {
        const int k0 = t * BKT;
        // stage A (8 x 32-row groups) and B (4 x 32-row groups)
        #pragma unroll
        for (int i = 0; i < 8; ++i)
            gload_lds16(aS + (size_t)i * 32 * D_DIM + k0,
                        (char*)sA + i * 4096 + w * 1024);
        #pragma unroll
        for (int i = 0; i < 4; ++i)
            gload_lds16(bS + (size_t)i * 32 * D_DIM + k0,
                        (char*)sB + i * 4096 + w * 1024);
        __syncthreads();

        #pragma unroll
        for (int kk = 0; kk < 2; ++kk) {
            const int swzk = kk ? swz1 : swz0;
            short8 a[8], b[4];
            #pragma unroll
            for (int mi = 0; mi < 8; ++mi)
                a[mi] = *(const short8*)(sAb + mi * 16 * 128 + swzk);
            #pragma unroll
            for (int ni = 0; ni < 4; ++ni)
                b[ni] = *(const short8*)(sBb + ni * 16 * 128 + swzk);
            #pragma unroll
            for (int mi = 0; mi < 8; ++mi)
                #pragma unroll
                for (int ni = 0; ni < 4; ++ni)
                    acc[mi][ni] = __builtin_amdgcn_mfma_f32_16x16x32_bf16(
                        a[mi], b[ni], acc[mi][ni], 0, 0, 0);
        }
        __syncthreads();
    }

    // ---- fused epilogue: hyperbolic logits + lane-pair logsumexp ---------
    float* scx = (float*)sA;          // reuse LDS for the cx2 tile
    scx[tid] = cx2g[m0 + tid];        // 256 threads = 256 rows
    __syncthreads();

    const float gam = gamma_p[0];
    const float ex  = expf(2.0f * gam);
    const float ch2 = ex + 1.0f / ex;           // 2*cosh(2*gamma)
    const float sh  = 0.5f * (ex - 1.0f / ex);  // sinh(2*gamma)

    const int  pan = (n0 >> 6) + wn;            // 64-col panel index
    const int  cls = pan * 8 + (lane & 7);
    const bool wrt = ((lane & 8) == 0) && (cls < C_CLS);
    const float w2 = (cls < C_CLS) ? 2.0f * wgl[cls] : 0.0f;

    #pragma unroll
    for (int mi = 0; mi < 8; ++mi) {
        #pragma unroll
        for (int r = 0; r < 4; ++r) {
            const int mloc = wm * 128 + mi * 16 + ((lane >> 4) << 2) + r;
            const float c2   = scx[mloc];
            const float rden = 1.0f / fmaxf(1.0f - c2, 1e-15f);
            const float tc   = ch2 * rden;
            const float tp   = (1.0f + c2) * sh * rden;
            float bk[4];
            #pragma unroll
            for (int ni = 0; ni < 4; ++ni) {
                const float t = fmaf(acc[mi][ni][r], tc, -tp);
                const float u = fmaxf(t + __fsqrt_rn(fmaf(t, t, 1.0f)), 1e-20f);
                bk[ni] = w2 * __logf(u);
            }
            float mx = fmaxf(fmaxf(bk[0], bk[1]), fmaxf(bk[2], bk[3]));
            mx = fmaxf(mx, __shfl_xor(mx, 8));
            float s = __expf(bk[0] - mx) + __expf(bk[1] - mx)
                    + __expf(bk[2] - mx) + __expf(bk[3] - mx);
            s += __shfl_xor(s, 8);
            if (wrt)
                out[(size_t)(m0 + mloc) * C_CLS + cls] = mx + __logf(s);
        }
    }
}

// --- launch ----------------------------------------------------------------

extern "C" void kernel_launch(void* const* d_in, const int* in_sizes, int n_in,
                              void* d_out, int out_size, void* d_ws, size_t ws_size,
                              hipStream_t stream) {
    const float* x     = (const float*)d_in[0];
    const float* wv    = (const float*)d_in[1];
    const float* wg    = (const float*)d_in[2];
    const float* gamma = (const float*)d_in[3];
    float* out = (float*)d_out;

    char* ws = (char*)d_ws;
    ushort* xb  = (ushort*)ws;                                  // 16,777,216 B
    ushort* zb  = (ushort*)(ws + (size_t)B_ROWS * D_DIM * 2);   // 16,515,072 B
    float*  cx2 = (float*)(ws + (size_t)B_ROWS * D_DIM * 2
                              + (size_t)N_PAD * D_DIM * 2);     //     32,768 B

    prep_z<<<N_PAD, 256, 0, stream>>>(wv, zb);
    prep_x<<<B_ROWS, 256, 0, stream>>>(x, xb, cx2);
    gemm_epi<<<32 * 63, 256, 0, stream>>>(xb, zb, cx2, wg, gamma, out);
}